// Round 11
// baseline (132.012 us; speedup 1.0000x reference)
//
#include <hip/hip_runtime.h>
#include <hip/hip_bf16.h>
#include <math.h>

typedef __attribute__((ext_vector_type(8))) short bf16x8;
typedef __attribute__((ext_vector_type(4))) float f32x4;

#define N_ROWS 8192
#define D_DIM  768
#define P_DIM  1024
#define KNOTS  17
#define NK     16                 // knots 1..16 (k=0 term is exactly zero)
#define NCH    128                // partial chunks: 64 row-blocks x 2 wr-halves
#define KSTEPS 12                 // 768 / 64
#define ALD    72                 // padded LDS row stride for A (bf16 elems)

// ---- bf16 RNE via bit trick (small prep kernels) ----
__device__ inline unsigned short f2bf(float f) {
    union { float f; unsigned int u; } x; x.f = f;
    unsigned int r = x.u + 0x7FFFu + ((x.u >> 16) & 1u);
    return (unsigned short)(r >> 16);
}

// ---- 8x f32 -> bf16x8 via compiler casts (backend emits v_cvt_pk_bf16_f32) ----
__device__ inline unsigned short bfbits(float f) {
    union { __hip_bfloat16 h; unsigned short u; } c;
    c.h = __float2bfloat16(f);
    return c.u;
}
__device__ inline bf16x8 pack8(float4 a, float4 b) {
    union { unsigned short s[8]; bf16x8 v; } r;
    r.s[0] = bfbits(a.x); r.s[1] = bfbits(a.y); r.s[2] = bfbits(a.z); r.s[3] = bfbits(a.w);
    r.s[4] = bfbits(b.x); r.s[5] = bfbits(b.y); r.s[6] = bfbits(b.z); r.s[7] = bfbits(b.w);
    return r.v;
}

// ---------------- K1: column sum-of-squares partials (no atomics) ----------
__global__ __launch_bounds__(256) void colsq_kernel(const float* __restrict__ a,
                                                    float* __restrict__ cpart) {
    int p  = blockIdx.x * 256 + threadIdx.x;
    int d0 = blockIdx.y * 64;
    float s = 0.f;
    for (int d = 0; d < 64; ++d) {
        float v = a[(size_t)(d0 + d) * P_DIM + p];
        s = fmaf(v, v, s);
    }
    cpart[(size_t)blockIdx.y * P_DIM + p] = s;
}

// ------- K2: a (768x1024) -> Bt (1024x768 bf16), normalized columns --------
__global__ __launch_bounds__(256) void atconv_kernel(const float* __restrict__ a,
                                                     const float* __restrict__ cpart,
                                                     unsigned short* __restrict__ Bt) {
    __shared__ float tile[64][65];
    __shared__ float linv[64];
    const int d0 = blockIdx.x * 64, p0 = blockIdx.y * 64;
    const int tid = threadIdx.x;
    if (tid < 64) {
        float s = 0.f;
        #pragma unroll
        for (int j = 0; j < D_DIM / 64; ++j)
            s += cpart[(size_t)j * P_DIM + p0 + tid];
        linv[tid] = rsqrtf(s);
    }
    #pragma unroll
    for (int pass = 0; pass < 16; ++pass) {
        int idx = pass * 256 + tid;
        int dr = idx >> 6, pc = idx & 63;
        tile[dr][pc] = a[(size_t)(d0 + dr) * P_DIM + p0 + pc];
    }
    __syncthreads();
    #pragma unroll
    for (int pass = 0; pass < 16; ++pass) {
        int idx = pass * 256 + tid;
        int pr = idx >> 6, dc = idx & 63;
        Bt[(size_t)(p0 + pr) * D_DIM + d0 + dc] = f2bf(tile[dc][pr] * linv[pr]);
    }
}

// ------- K3: fused GEMM + cos/sin partials ---------------------------------
// 128x128 tile, 512 thr = 8 waves (2wr x 4wc), BK=64.
// A: reg-staged fp32->bf16 into padded dbuf LDS (stride 72, 2-way banks=free).
// B: per-lane DIRECT global->reg fragment loads (Bt is L2-resident; same
//    element mapping as the proven LDS read). No global_load_lds, no vmem
//    drain at barriers, no B swizzle. One lgkm-only barrier per K-step.
__global__ __launch_bounds__(512, 4) void gemmcf_kernel(const float* __restrict__ Z,
                                                        const unsigned short* __restrict__ B,
                                                        float* __restrict__ part) {
    __shared__ unsigned short AsB[2][128 * ALD];
    const int tid  = threadIdx.x;
    const int lane = tid & 63;
    const int wave = tid >> 6;            // 0..7
    const int wr = wave >> 2, wc = wave & 3;

    // T1: XCD-aware swizzle (512 blocks, 8 XCDs, 64 blocks/XCD = 8 row-panels)
    const int bid = blockIdx.x + blockIdx.y * 8;
    const int swz = (bid & 7) * 64 + (bid >> 3);
    const int bx = swz & 7, by = swz >> 3;
    const int row0 = by * 128;
    const int col0 = bx * 128;

    // A reg-staging geometry: lane covers tile-row aR, chunks {ac, ac+4} of 8
    const int aR = wave * 16 + (lane >> 2);
    const int ac = lane & 3;
    const float* Zg = Z + (size_t)(row0 + aR) * D_DIM + ac * 8;

    // B direct-fragment pointers (ni = 0,1); kg = kk*4 + (lane>>4)
    const unsigned short* Bg0 =
        B + (size_t)(col0 + wc * 32 + (lane & 15)) * D_DIM + (lane >> 4) * 8;
    const unsigned short* Bg1 = Bg0 + (size_t)16 * D_DIM;

    float4 ar0, ar1, ar2, ar3;            // A(t+1) in flight (16 fp32)

#define ALOAD(kt) do { const float* zp_ = Zg + (kt) * 64;                    \
        ar0 = *reinterpret_cast<const float4*>(zp_);                         \
        ar1 = *reinterpret_cast<const float4*>(zp_ + 4);                     \
        ar2 = *reinterpret_cast<const float4*>(zp_ + 32);                    \
        ar3 = *reinterpret_cast<const float4*>(zp_ + 36); } while (0)
#define AWRITE(db) do {                                                      \
        *reinterpret_cast<bf16x8*>(&AsB[db][aR * ALD + ac * 8])       = pack8(ar0, ar1); \
        *reinterpret_cast<bf16x8*>(&AsB[db][aR * ALD + (ac + 4) * 8]) = pack8(ar2, ar3); } while (0)
#define LGKM_BARRIER() do {                                                  \
        asm volatile("s_waitcnt lgkmcnt(0)" ::: "memory");                   \
        __builtin_amdgcn_sched_barrier(0);                                   \
        __builtin_amdgcn_s_barrier(); } while (0)

    f32x4 acc[4][2] = {};

    // prologue: A(0) -> buf0 (compiler auto-waits regs); A(1) left in flight
    ALOAD(0);
    AWRITE(0);
    ALOAD(1);
    LGKM_BARRIER();

    #pragma unroll
    for (int t = 0; t < KSTEPS; ++t) {
        const int cur = t & 1;
        if (t + 1 < KSTEPS) AWRITE(cur ^ 1);   // ar = A(t+1); auto vmcnt wait
        // B fragments for this step, straight from L2 (no barrier coupling)
        const bf16x8 b00 = *reinterpret_cast<const bf16x8*>(Bg0 + t * 64);
        const bf16x8 b01 = *reinterpret_cast<const bf16x8*>(Bg1 + t * 64);
        const bf16x8 b10 = *reinterpret_cast<const bf16x8*>(Bg0 + t * 64 + 32);
        const bf16x8 b11 = *reinterpret_cast<const bf16x8*>(Bg1 + t * 64 + 32);
        #pragma unroll
        for (int kk = 0; kk < 2; ++kk) {
            bf16x8 af[4];
            const int kg = kk * 4 + (lane >> 4);
            #pragma unroll
            for (int mi = 0; mi < 4; ++mi)
                af[mi] = *reinterpret_cast<const bf16x8*>(
                    &AsB[cur][(wr * 64 + mi * 16 + (lane & 15)) * ALD + kg * 8]);
            const bf16x8 bn0 = kk ? b10 : b00;
            const bf16x8 bn1 = kk ? b11 : b01;
            #pragma unroll
            for (int mi = 0; mi < 4; ++mi) {
                acc[mi][0] = __builtin_amdgcn_mfma_f32_16x16x32_bf16(
                    af[mi], bn0, acc[mi][0], 0, 0, 0);
                acc[mi][1] = __builtin_amdgcn_mfma_f32_16x16x32_bf16(
                    af[mi], bn1, acc[mi][1], 0, 0, 0);
            }
        }
        if (t + 2 < KSTEPS) ALOAD(t + 2);      // issue late: ar dead in compute
        if (t + 1 < KSTEPS) LGKM_BARRIER();
    }
#undef ALOAD
#undef AWRITE
#undef LGKM_BARRIER

    // ---- fused epilogue: per-column cos/sin sums over this wave's 64 rows.
    const float dt = 0.1875f;   // 3/16 exact
    #pragma unroll
    for (int ni = 0; ni < 2; ++ni) {
        float cs[NK], ss[NK];
        #pragma unroll
        for (int k = 0; k < NK; ++k) { cs[k] = 0.f; ss[k] = 0.f; }
        #pragma unroll
        for (int mi = 0; mi < 4; ++mi)
            #pragma unroll
            for (int j = 0; j < 4; ++j) {
                float th = acc[mi][ni][j] * dt;
                float s1 = __sinf(th);
                float c1 = __cosf(th);
                float c2 = 2.f * c1;
                float ckm2 = 1.f, skm2 = 0.f;
                float ckm1 = c1,  skm1 = s1;
                cs[0] += c1; ss[0] += s1;            // k = 1
                #pragma unroll
                for (int k = 2; k <= NK; ++k) {
                    float ck = fmaf(c2, ckm1, -ckm2);
                    float sk = fmaf(c2, skm1, -skm2);
                    cs[k - 1] += ck; ss[k - 1] += sk;
                    ckm2 = ckm1; skm2 = skm1;
                    ckm1 = ck;   skm1 = sk;
                }
            }
        #pragma unroll
        for (int k = 0; k < NK; ++k) {
            cs[k] += __shfl_xor(cs[k], 16);
            cs[k] += __shfl_xor(cs[k], 32);
            ss[k] += __shfl_xor(ss[k], 16);
            ss[k] += __shfl_xor(ss[k], 32);
        }
        if (lane < 16) {
            int col = col0 + wc * 32 + ni * 16 + lane;
            size_t base = ((size_t)(by * 2 + wr) * 2 * NK) * P_DIM + col;
            #pragma unroll
            for (int k = 0; k < NK; ++k) {
                part[base + (size_t)k * P_DIM]        = cs[k];
                part[base + (size_t)(NK + k) * P_DIM] = ss[k];
            }
        }
    }
}

// ---------------- K4: parallel chunk reduction (32*1024 outputs) -----------
__global__ __launch_bounds__(256) void red1_kernel(const float* __restrict__ part,
                                                   float* __restrict__ sums) {
    int g = blockIdx.x * 256 + threadIdx.x;   // [0, 2*NK*1024)
    float s = 0.f;
    for (int c = 0; c < NCH; ++c)
        s += part[(size_t)c * 2 * NK * P_DIM + g];
    sums[g] = s;
}

// ---------------- K5: epilogue + scalar out --------------------------------
__global__ __launch_bounds__(1024) void red2_kernel(const float* __restrict__ sums,
                                                    float* __restrict__ out) {
    const int p = threadIdx.x;
    const float dt = 0.1875f;
    const float inv_n = 1.0f / (float)N_ROWS;
    float contrib = 0.f;
    #pragma unroll
    for (int k = 1; k <= NK; ++k) {
        float cm   = sums[(k - 1) * P_DIM + p] * inv_n;
        float sm   = sums[(NK + k - 1) * P_DIM + p] * inv_n;
        float tk   = dt * (float)k;
        float phik = expf(-0.5f * tk * tk);
        float wk   = (k == KNOTS - 1) ? dt : 2.f * dt;
        float d    = cm - phik;
        contrib += wk * phik * (d * d + sm * sm);
    }
    __shared__ float red[1024];
    red[p] = contrib;
    __syncthreads();
    for (int sft = 512; sft > 0; sft >>= 1) {
        if (p < sft) red[p] += red[p + sft];
        __syncthreads();
    }
    if (p == 0) out[0] = red[0] * (float)N_ROWS / (float)P_DIM;
}

extern "C" void kernel_launch(void* const* d_in, const int* in_sizes, int n_in,
                              void* d_out, int out_size, void* d_ws, size_t ws_size,
                              hipStream_t stream) {
    const float* z = (const float*)d_in[0];   // 8192 x 768
    const float* a = (const float*)d_in[1];   // 768 x 1024
    float* out = (float*)d_out;

    char* ws = (char*)d_ws;                                       // ~18.5 MB used
    float*          cpart = (float*)ws;                           // 48 KB (pad 64K)
    unsigned short* Bt    = (unsigned short*)(ws + 65536);        // 1.5 MB
    float*          part  = (float*)(ws + 65536 + 1572864);       // 16.8 MB
    float*          sums  = (float*)(ws + 65536 + 1572864 + 16777216); // 128 KB

    colsq_kernel<<<dim3(P_DIM / 256, D_DIM / 64), 256, 0, stream>>>(a, cpart);
    atconv_kernel<<<dim3(D_DIM / 64, P_DIM / 64), 256, 0, stream>>>(a, cpart, Bt);
    gemmcf_kernel<<<dim3(P_DIM / 128, N_ROWS / 128), 512, 0, stream>>>(z, Bt, part);
    red1_kernel<<<dim3(2 * NK * P_DIM / 256), 256, 0, stream>>>(part, sums);
    red2_kernel<<<1, 1024, 0, stream>>>(sums, out);
}

// Round 12
// 113.056 us; speedup vs baseline: 1.1677x; 1.1677x over previous
//
#include <hip/hip_runtime.h>
#include <math.h>

typedef __attribute__((ext_vector_type(8))) short bf16x8;
typedef __attribute__((ext_vector_type(4))) float f32x4;

#define N_ROWS 8192
#define D_DIM  768
#define P_DIM  1024
#define KNOTS  17
#define NK     16                 // knots 1..16 (k=0 term is exactly zero)
#define KSTEPS 12                 // 768 / 64

// ---- bf16 round-to-nearest-even (finite data only) ----
__device__ inline unsigned short f2bf(float f) {
    union { float f; unsigned int u; } x; x.f = f;
    unsigned int r = x.u + 0x7FFFu + ((x.u >> 16) & 1u);
    return (unsigned short)(r >> 16);
}

// ---- async global->LDS, 16B per lane (LDS base wave-uniform, HW adds lane*16)
__device__ inline void gload_lds16(const unsigned short* g, const unsigned short* l) {
    auto gp = reinterpret_cast<const __attribute__((address_space(1))) char*>(
        reinterpret_cast<uintptr_t>(g));
    auto lp = reinterpret_cast<__attribute__((address_space(3))) char*>(
        (uintptr_t)(unsigned int)reinterpret_cast<uintptr_t>(l));
    __builtin_amdgcn_global_load_lds(gp, lp, 16, 0, 0);
}

// ---------------- K1: column sum-of-squares partials (no atomics) ----------
__global__ __launch_bounds__(256) void colsq_kernel(const float* __restrict__ a,
                                                    float* __restrict__ cpart) {
    int p  = blockIdx.x * 256 + threadIdx.x;
    int d0 = blockIdx.y * 64;
    float s = 0.f;
    for (int d = 0; d < 64; ++d) {
        float v = a[(size_t)(d0 + d) * P_DIM + p];
        s = fmaf(v, v, s);
    }
    cpart[(size_t)blockIdx.y * P_DIM + p] = s;
}

// ---------------- K2: z (fp32) -> zh (bf16), elementwise -------------------
__global__ __launch_bounds__(256) void zconv_kernel(const float* __restrict__ z,
                                                    unsigned short* __restrict__ zh) {
    size_t i = ((size_t)blockIdx.x * 256 + threadIdx.x) * 4;
    float4 v = *reinterpret_cast<const float4*>(z + i);
    ushort4 o;
    o.x = f2bf(v.x); o.y = f2bf(v.y); o.z = f2bf(v.z); o.w = f2bf(v.w);
    *reinterpret_cast<ushort4*>(zh + i) = o;
}

// ------- K3: a (768x1024) -> Bt (1024x768 bf16), normalized columns --------
__global__ __launch_bounds__(256) void atconv_kernel(const float* __restrict__ a,
                                                     const float* __restrict__ cpart,
                                                     unsigned short* __restrict__ Bt) {
    __shared__ float tile[64][65];
    __shared__ float linv[64];
    const int d0 = blockIdx.x * 64, p0 = blockIdx.y * 64;
    const int tid = threadIdx.x;
    if (tid < 64) {
        float s = 0.f;
        #pragma unroll
        for (int j = 0; j < D_DIM / 64; ++j)
            s += cpart[(size_t)j * P_DIM + p0 + tid];
        linv[tid] = rsqrtf(s);
    }
    #pragma unroll
    for (int pass = 0; pass < 16; ++pass) {
        int idx = pass * 256 + tid;
        int dr = idx >> 6, pc = idx & 63;
        tile[dr][pc] = a[(size_t)(d0 + dr) * P_DIM + p0 + pc];
    }
    __syncthreads();
    #pragma unroll
    for (int pass = 0; pass < 16; ++pass) {
        int idx = pass * 256 + tid;
        int pr = idx >> 6, dc = idx & 63;
        Bt[(size_t)(p0 + pr) * D_DIM + d0 + dc] = f2bf(tile[dc][pr] * linv[pr]);
    }
}

// ------- K4: fused bf16 MFMA GEMM + sincos/Chebyshev -> atomic sums --------
// r7 core (fastest measured): 128x128 tile, 512 thr = 8 waves (2wr x 4wc),
// BK=64, dbuf LDS, gload_lds both operands, counted vmcnt(4), XOR-swizzled
// source + swizzled LDS read. Epilogue adds into global sums via fp32 atomics.
__global__ __launch_bounds__(512, 4) void gemmcf_kernel(const unsigned short* __restrict__ A,
                                                        const unsigned short* __restrict__ B,
                                                        float* __restrict__ sums) {
    __shared__ unsigned short AsB[2][128 * 64];
    __shared__ unsigned short BsB[2][128 * 64];
    const int tid  = threadIdx.x;
    const int lane = tid & 63;
    const int wave = tid >> 6;            // 0..7
    const int wr = wave >> 2, wc = wave & 3;

    // T1: XCD-aware swizzle (512 blocks, 8 XCDs, 64 blocks/XCD = 8 row-panels)
    const int bid = blockIdx.x + blockIdx.y * 8;
    const int swz = (bid & 7) * 64 + (bid >> 3);
    const int bx = swz & 7, by = swz >> 3;
    const int row0 = by * 128;
    const int col0 = bx * 128;

    // staging: wave stages rows [wave*16, +16); source chunk pre-swizzled
    const int srow = wave * 16 + (lane >> 3);
    const int sc   = (lane & 7) ^ ((lane >> 3) & 7);   // involution pre-swizzle
    const unsigned short* Ag = A + (size_t)(row0 + srow) * D_DIM + sc * 8;
    const unsigned short* Bg = B + (size_t)(col0 + srow) * D_DIM + sc * 8;
    const int ldsw = wave * 16 * 64;      // wave-uniform LDS base (elements)

#define STAGE(kt, db)  do { const int k0_ = (kt) * 64;                       \
        gload_lds16(Ag + k0_,             &AsB[db][ldsw]);                   \
        gload_lds16(Ag + k0_ + 8 * D_DIM, &AsB[db][ldsw + 8 * 64]);          \
        gload_lds16(Bg + k0_,             &BsB[db][ldsw]);                   \
        gload_lds16(Bg + k0_ + 8 * D_DIM, &BsB[db][ldsw + 8 * 64]); } while (0)

    f32x4 acc[4][2] = {};

    STAGE(0, 0);
    #pragma unroll
    for (int t = 0; t < KSTEPS; ++t) {
        const int cur = t & 1;
        if (t + 1 < KSTEPS) {
            STAGE(t + 1, cur ^ 1);
            asm volatile("s_waitcnt vmcnt(4)" ::: "memory");
        } else {
            asm volatile("s_waitcnt vmcnt(0)" ::: "memory");
        }
        __builtin_amdgcn_sched_barrier(0);
        __builtin_amdgcn_s_barrier();
        #pragma unroll
        for (int kk = 0; kk < 2; ++kk) {
            bf16x8 af[4], bfr[2];
            const int kg = kk * 4 + (lane >> 4);
            const int kph = (kg ^ (lane & 7)) * 8;     // swizzled read chunk
            #pragma unroll
            for (int mi = 0; mi < 4; ++mi)
                af[mi] = *reinterpret_cast<const bf16x8*>(
                    &AsB[cur][(wr * 64 + mi * 16 + (lane & 15)) * 64 + kph]);
            #pragma unroll
            for (int ni = 0; ni < 2; ++ni)
                bfr[ni] = *reinterpret_cast<const bf16x8*>(
                    &BsB[cur][(wc * 32 + ni * 16 + (lane & 15)) * 64 + kph]);
            #pragma unroll
            for (int mi = 0; mi < 4; ++mi)
                #pragma unroll
                for (int ni = 0; ni < 2; ++ni)
                    acc[mi][ni] = __builtin_amdgcn_mfma_f32_16x16x32_bf16(
                        af[mi], bfr[ni], acc[mi][ni], 0, 0, 0);
        }
        __builtin_amdgcn_s_barrier();
    }
#undef STAGE

    // ---- fused epilogue: per-column cos/sin sums over this wave's 64 rows.
    // col = wc*32 + ni*16 + (lane&15); 16 values (mi,j) are rows of that one
    // column; butterfly 16/32 merges quarters; atomics merge everything else.
    const float dt = 0.1875f;   // 3/16 exact
    #pragma unroll
    for (int ni = 0; ni < 2; ++ni) {
        float cs[NK], ss[NK];
        #pragma unroll
        for (int k = 0; k < NK; ++k) { cs[k] = 0.f; ss[k] = 0.f; }
        #pragma unroll
        for (int mi = 0; mi < 4; ++mi)
            #pragma unroll
            for (int j = 0; j < 4; ++j) {
                float th = acc[mi][ni][j] * dt;
                float s1 = __sinf(th);
                float c1 = __cosf(th);
                float c2 = 2.f * c1;
                float ckm2 = 1.f, skm2 = 0.f;
                float ckm1 = c1,  skm1 = s1;
                cs[0] += c1; ss[0] += s1;            // k = 1
                #pragma unroll
                for (int k = 2; k <= NK; ++k) {
                    float ck = fmaf(c2, ckm1, -ckm2);
                    float sk = fmaf(c2, skm1, -skm2);
                    cs[k - 1] += ck; ss[k - 1] += sk;
                    ckm2 = ckm1; skm2 = skm1;
                    ckm1 = ck;   skm1 = sk;
                }
            }
        #pragma unroll
        for (int k = 0; k < NK; ++k) {
            cs[k] += __shfl_xor(cs[k], 16);
            cs[k] += __shfl_xor(cs[k], 32);
            ss[k] += __shfl_xor(ss[k], 16);
            ss[k] += __shfl_xor(ss[k], 32);
        }
        if (lane < 16) {
            int col = col0 + wc * 32 + ni * 16 + lane;
            #pragma unroll
            for (int k = 0; k < NK; ++k) {
                atomicAdd(&sums[(size_t)k * P_DIM + col],        cs[k]);
                atomicAdd(&sums[(size_t)(NK + k) * P_DIM + col], ss[k]);
            }
        }
    }
}

// ---------------- K5: epilogue + scalar out --------------------------------
__global__ __launch_bounds__(1024) void red2_kernel(const float* __restrict__ sums,
                                                    float* __restrict__ out) {
    const int p = threadIdx.x;
    const float dt = 0.1875f;
    const float inv_n = 1.0f / (float)N_ROWS;
    float contrib = 0.f;
    #pragma unroll
    for (int k = 1; k <= NK; ++k) {
        float cm   = sums[(k - 1) * P_DIM + p] * inv_n;
        float sm   = sums[(NK + k - 1) * P_DIM + p] * inv_n;
        float tk   = dt * (float)k;
        float phik = expf(-0.5f * tk * tk);
        float wk   = (k == KNOTS - 1) ? dt : 2.f * dt;
        float d    = cm - phik;
        contrib += wk * phik * (d * d + sm * sm);
    }
    __shared__ float red[1024];
    red[p] = contrib;
    __syncthreads();
    for (int sft = 512; sft > 0; sft >>= 1) {
        if (p < sft) red[p] += red[p + sft];
        __syncthreads();
    }
    if (p == 0) out[0] = red[0] * (float)N_ROWS / (float)P_DIM;
}

extern "C" void kernel_launch(void* const* d_in, const int* in_sizes, int n_in,
                              void* d_out, int out_size, void* d_ws, size_t ws_size,
                              hipStream_t stream) {
    const float* z = (const float*)d_in[0];   // 8192 x 768
    const float* a = (const float*)d_in[1];   // 768 x 1024
    float* out = (float*)d_out;

    char* ws = (char*)d_ws;                                       // ~14.4 MB used
    float*          cpart = (float*)ws;                           // 48 KB (pad 64K)
    float*          sums  = (float*)(ws + 65536);                 // 128 KB
    unsigned short* zh    = (unsigned short*)(ws + 65536 + 131072);            // 12.6 MB
    unsigned short* Bt    = (unsigned short*)(ws + 65536 + 131072 + 12582912); // 1.5 MB

    hipMemsetAsync(sums, 0, 2 * NK * P_DIM * sizeof(float), stream);
    colsq_kernel<<<dim3(P_DIM / 256, D_DIM / 64), 256, 0, stream>>>(a, cpart);
    zconv_kernel<<<dim3(N_ROWS * D_DIM / (256 * 4)), 256, 0, stream>>>(z, zh);
    atconv_kernel<<<dim3(D_DIM / 64, P_DIM / 64), 256, 0, stream>>>(a, cpart, Bt);
    gemmcf_kernel<<<dim3(P_DIM / 128, N_ROWS / 128), 512, 0, stream>>>(zh, Bt, sums);
    red2_kernel<<<1, 1024, 0, stream>>>(sums, out);
}